// Round 2
// baseline (244.639 us; speedup 1.0000x reference)
//
#include <hip/hip_runtime.h>

#define BB 8
#define CC_TOT 64
#define HH 128
#define WW 256
#define DD 64
#define CCHUNK 16          // channels of the right row staged per LDS chunk
#define RPAD 64            // zero pad left of right-row (handles w-d < 0 exactly)
#define RW (WW + RPAD)     // 320 floats per row

// volume[b,d,h,w] = (1/64) * sum_c L[b,c,h,w] * R[b,c,h,w-d]   (0 when w<d)
//
// Tiling: one block per (b,h). 256 threads:
//   wlane = tid & 31  -> w0 = wlane*8   (32 lanes cover W=256, 8 w each)
//   dgrp  = tid >> 5  -> d0 = dgrp*8    (8 groups cover D=64, 8 d each)
// Per thread: acc[8d][8w]. Per channel: 2 global float4 (L, L1-cached) +
// 4 ds_read_b128 (R window, 16 floats covers j = 8-dd+i in [1,15]) -> 64 FMA.
// LDS holds ONLY the right rows (20 KiB) -> 8 blocks/CU by LDS.
__global__ __launch_bounds__(256, 4)
void corr_volume_kernel(const float* __restrict__ left,
                        const float* __restrict__ right,
                        float* __restrict__ out) {
    __shared__ alignas(16) float ldsR[CCHUNK][RW];   // 20 KiB

    const int tid = threadIdx.x;
    const int bh  = blockIdx.x;
    const int b   = bh >> 7;     // / 128
    const int h   = bh & 127;

    const int wlane = tid & 31;
    const int dgrp  = tid >> 5;    // 0..7
    const int w0    = wlane * 8;
    const int d0    = dgrp * 8;

    // Zero the pad: CCHUNK*RPAD = 1024 floats = 256 float4, one per thread.
    {
        const float4 z = {0.f, 0.f, 0.f, 0.f};
        int cc = tid >> 4;          // 16 float4 of pad per row
        int p4 = tid & 15;
        *(float4*)&ldsR[cc][p4 * 4] = z;
    }

    float acc[8][8];
    #pragma unroll
    for (int dd = 0; dd < 8; ++dd)
        #pragma unroll
        for (int i = 0; i < 8; ++i)
            acc[dd][i] = 0.0f;

    const size_t chanStride = (size_t)HH * WW;                       // 32768
    const size_t rowBase    = (size_t)b * CC_TOT * chanStride + (size_t)h * WW;
    const float* lp0 = left + rowBase + w0;   // this thread's L pointer (c=0)

    for (int c0 = 0; c0 < CC_TOT; c0 += CCHUNK) {
        __syncthreads();   // previous chunk's reads done (also orders pad init)
        // Stage CCHUNK right rows: 16 rows x 64 float4 = 1024, 4 per thread.
        #pragma unroll
        for (int i = 0; i < 4; ++i) {
            int f  = i * 256 + tid;
            int cc = f >> 6;
            int w4 = f & 63;
            float4 rv = ((const float4*)(right + rowBase +
                         (size_t)(c0 + cc) * chanStride))[w4];
            *(float4*)&ldsR[cc][RPAD + w4 * 4] = rv;
        }
        __syncthreads();

        #pragma unroll
        for (int cc = 0; cc < CCHUNK; ++cc) {
            // Left: 8 floats straight from global (L1/L2-resident row).
            const float* lp = lp0 + (size_t)(c0 + cc) * chanStride;
            float4 La = *(const float4*)(lp);
            float4 Lb = *(const float4*)(lp + 4);
            float Lr[8] = {La.x, La.y, La.z, La.w, Lb.x, Lb.y, Lb.z, Lb.w};

            // Right window from LDS: 16 floats starting at s0 = w0-d0-8
            // (32B-aligned; pad makes s<0 exactly zero).
            const float* rbase = &ldsR[cc][RPAD + w0 - d0 - 8];
            float rv[16];
            #pragma unroll
            for (int k = 0; k < 4; ++k) {
                float4 v = *(const float4*)(rbase + 4 * k);
                rv[4 * k + 0] = v.x;
                rv[4 * k + 1] = v.y;
                rv[4 * k + 2] = v.z;
                rv[4 * k + 3] = v.w;
            }

            // j = (w0+i - (d0+dd)) - s0 = 8 - dd + i  in [1,15]
            #pragma unroll
            for (int dd = 0; dd < 8; ++dd) {
                #pragma unroll
                for (int i = 0; i < 8; ++i) {
                    acc[dd][i] = fmaf(Lr[i], rv[8 - dd + i], acc[dd][i]);
                }
            }
        }
    }

    // Epilogue: scale by 1/64; invalid (w<d) entries are exact zeros already.
    const float scale = 1.0f / 64.0f;
    #pragma unroll
    for (int dd = 0; dd < 8; ++dd) {
        int d = d0 + dd;
        float* op = out + (((size_t)b * DD + d) * HH + h) * (size_t)WW + w0;
        float4 o0, o1;
        o0.x = acc[dd][0] * scale; o0.y = acc[dd][1] * scale;
        o0.z = acc[dd][2] * scale; o0.w = acc[dd][3] * scale;
        o1.x = acc[dd][4] * scale; o1.y = acc[dd][5] * scale;
        o1.z = acc[dd][6] * scale; o1.w = acc[dd][7] * scale;
        *(float4*)(op)     = o0;
        *(float4*)(op + 4) = o1;
    }
}

extern "C" void kernel_launch(void* const* d_in, const int* in_sizes, int n_in,
                              void* d_out, int out_size, void* d_ws, size_t ws_size,
                              hipStream_t stream) {
    const float* left  = (const float*)d_in[0];
    const float* right = (const float*)d_in[1];
    float* out = (float*)d_out;

    dim3 grid(BB * HH);   // 1024 blocks, one per (b, h) row
    dim3 block(256);
    corr_volume_kernel<<<grid, block, 0, stream>>>(left, right, out);
}

// Round 3
// 191.856 us; speedup vs baseline: 1.2751x; 1.2751x over previous
//
#include <hip/hip_runtime.h>

typedef _Float16 half8 __attribute__((ext_vector_type(8)));
typedef float floatx4 __attribute__((ext_vector_type(4)));

#define BB 8
#define CC 64
#define HH 128
#define WW 256
#define DD 64
#define KCH 32               // channels per K-chunk (one mfma K)
#define LROWS WW             // 256 rows of L  [w][c]
#define RROWS (WW + 64)      // 320 rows of R  [w'+64][c]; rows 0..63 = zeros (w'<0)

// out[b,d,h,w] = (1/64) sum_c L[b,c,h,w] * R[b,c,h,w-d], 0 where w<d.
// Banded Gram matrix via MFMA: C[m][n] = sum_k A[m][k]*B[k][n] with
//   A[m][k] = R[c=k][w'=s+m]  (A-frag: m=lane&15, k=quad*8+j)
//   B[k][n] = L[c=k][w=w0+n]  (B-frag: n=lane&15, k=quad*8+j)
// d = (w0+n) - (s+m). s = w0-64+16u, u=0..4 covers d in [0,63] exactly once.
// LDS rows are 32 halves (64B): fragment b128 reads hit each 4-bank window
// with exactly 8 lanes -> conflict-free.
__global__ __launch_bounds__(256, 3)
void corr_volume_mfma(const float* __restrict__ left,
                      const float* __restrict__ right,
                      float* __restrict__ out) {
    __shared__ _Float16 Lb[LROWS * KCH];   // 16 KiB
    __shared__ _Float16 Rb[RROWS * KCH];   // 20 KiB

    const int tid  = threadIdx.x;
    const int lane = tid & 63;
    const int wv   = tid >> 6;          // wave 0..3 -> w-range wv*64..wv*64+63
    const int n    = lane & 15;         // MFMA col index (also A-row index m)
    const int q    = lane >> 4;         // quad 0..3
    const int bh   = blockIdx.x;
    const int b    = bh >> 7;
    const int h    = bh & 127;

    const size_t chanStride = (size_t)HH * WW;                       // 32768
    const size_t rowBase    = (size_t)b * CC * chanStride + (size_t)h * WW;

    // Zero the w'<0 pad rows of Rb: 64 rows * 32 halves = 2048 = 256 thr * 8.
    {
        half8 z;
        #pragma unroll
        for (int t = 0; t < 8; ++t) z[t] = (_Float16)0.0f;
        *(half8*)&Rb[tid * 8] = z;
    }

    floatx4 acc[4][5];
    #pragma unroll
    for (int t = 0; t < 4; ++t)
        #pragma unroll
        for (int u = 0; u < 5; ++u)
            #pragma unroll
            for (int r = 0; r < 4; ++r)
                acc[t][u][r] = 0.0f;

    const int wbase = wv * 64;
    const float* lcol = left  + rowBase + tid;   // this thread's w-column
    const float* rcol = right + rowBase + tid;

    for (int ck = 0; ck < 2; ++ck) {
        __syncthreads();   // prior chunk's reads done (and pad init on ck=0)
        // Stage: thread tid owns L row w=tid and R row w'=tid (phys tid+64).
        // Global: 64-lane consecutive-w b32 loads (256B coalesced).
        const int cb = ck * KCH;
        _Float16* Lrow = &Lb[tid * KCH];
        _Float16* Rrow = &Rb[(tid + 64) * KCH];
        #pragma unroll
        for (int g = 0; g < 4; ++g) {
            float lv[8], rv[8];
            #pragma unroll
            for (int t = 0; t < 8; ++t) {
                lv[t] = lcol[(size_t)(cb + g * 8 + t) * chanStride];
                rv[t] = rcol[(size_t)(cb + g * 8 + t) * chanStride];
            }
            half8 lh, rh;
            #pragma unroll
            for (int t = 0; t < 8; ++t) {
                lh[t] = (_Float16)lv[t];
                rh[t] = (_Float16)rv[t];
            }
            // b128 LDS writes; ~2x bank pressure here is negligible (64/block)
            *(half8*)&Lrow[g * 8] = lh;
            *(half8*)&Rrow[g * 8] = rh;
        }
        __syncthreads();

        // Fragments: conflict-free b128 reads.
        half8 bfrag[4], afrag[8];
        #pragma unroll
        for (int t = 0; t < 4; ++t)
            bfrag[t] = *(const half8*)&Lb[(wbase + t * 16 + n) * KCH + q * 8];
        #pragma unroll
        for (int a = 0; a < 8; ++a)
            afrag[a] = *(const half8*)&Rb[(wbase + a * 16 + n) * KCH + q * 8];
        // Tile (t,u): w0 = wbase+16t, s = w0-64+16u -> A-frag index a = t+u.
        #pragma unroll
        for (int t = 0; t < 4; ++t)
            #pragma unroll
            for (int u = 0; u < 5; ++u)
                acc[t][u] = __builtin_amdgcn_mfma_f32_16x16x32_f16(
                    afrag[t + u], bfrag[t], acc[t][u], 0, 0, 0);
    }

    // Epilogue: C/D layout col=lane&15 (=n), row m_out = q*4+r.
    // d = 64 - 16u + n - m_out; store iff 0 <= d <= 63 (edge diagonals only).
    const float scale = 1.0f / 64.0f;
    #pragma unroll
    for (int t = 0; t < 4; ++t) {
        const int w = wbase + t * 16 + n;
        #pragma unroll
        for (int u = 0; u < 5; ++u) {
            #pragma unroll
            for (int r = 0; r < 4; ++r) {
                const int mo = q * 4 + r;
                const int d  = 64 - 16 * u + n - mo;
                if (d >= 0 && d <= 63) {
                    out[(((size_t)b * DD + d) * HH + h) * WW + w] =
                        acc[t][u][r] * scale;
                }
            }
        }
    }
}

extern "C" void kernel_launch(void* const* d_in, const int* in_sizes, int n_in,
                              void* d_out, int out_size, void* d_ws, size_t ws_size,
                              hipStream_t stream) {
    const float* left  = (const float*)d_in[0];
    const float* right = (const float*)d_in[1];
    float* out = (float*)d_out;

    dim3 grid(BB * HH);   // one block per (b, h)
    dim3 block(256);
    corr_volume_mfma<<<grid, block, 0, stream>>>(left, right, out);
}

// Round 4
// 189.258 us; speedup vs baseline: 1.2926x; 1.0137x over previous
//
#include <hip/hip_runtime.h>

typedef _Float16 half8 __attribute__((ext_vector_type(8)));
typedef float floatx4 __attribute__((ext_vector_type(4)));

#define BB 8
#define CC 64
#define HH 128
#define WW 256
#define DD 64

// out[b,d,h,w] = (1/64) sum_c L[b,c,h,w] * R[b,c,h,w-d], 0 where w<d.
// Banded Gram matrix via mfma_f32_16x16x32_f16:
//   A[m][k] = R[c=k][w'=s+m], B[k][n] = L[c=k][w=w0+n], s = w0-64+16u.
//   d = 64 - 16u + n - m, u=0..4 tiles d in [0,63] exactly once.
//
// One block per (b,h), 512 threads (8 waves), single K pass (all 64 ch).
// LDS [w][c] fp16, rows of 64 halves (128 B), column groups of 8 halves
// XOR-swizzled by (w&7): fragment ds_read_b128 stays at the conflict-free
// minimum (8 lanes per 4-bank window); staging writes spread to 2 windows.
// Staging: thread owns 4 consecutive w x 8 channels -> 16 dwordx4 global
// loads (fully coalesced, max MLP), in-register transpose, 8 b128 writes.
__global__ __launch_bounds__(512, 4)
void corr_volume_mfma(const float* __restrict__ left,
                      const float* __restrict__ right,
                      float* __restrict__ out) {
    __shared__ _Float16 Lb[256 * 64];   // [w][c^swz]      32 KiB
    __shared__ _Float16 Rb[320 * 64];   // [w'+64][c^swz]  40 KiB (rows 0..63 = 0)

    const int tid  = threadIdx.x;
    const int lane = tid & 63;
    const int wv   = tid >> 6;          // wave 0..7
    const int bh   = blockIdx.x;
    const int b    = bh >> 7;
    const int h    = bh & 127;

    const size_t chanStride = (size_t)HH * WW;                      // 32768
    const size_t rowBase    = (size_t)b * CC * chanStride + (size_t)h * WW;

    // ---------------- staging ----------------
    const int sw = lane * 4;            // w rows sw..sw+3
    const int cg = wv;                  // channel group: channels cg*8..cg*8+7

    const float* lp = left  + rowBase + (size_t)(cg * 8) * chanStride + sw;
    const float* rp = right + rowBase + (size_t)(cg * 8) * chanStride + sw;

    float4 lv[8], rv[8];
    #pragma unroll
    for (int cc = 0; cc < 8; ++cc) {
        lv[cc] = *(const float4*)(lp + (size_t)cc * chanStride);
        rv[cc] = *(const float4*)(rp + (size_t)cc * chanStride);
    }

    // Zero the w'<0 pad rows while loads are in flight:
    // 64 rows * 64 halves = 4096 halves = 512 threads * 1 half8.
    {
        half8 z = {0, 0, 0, 0, 0, 0, 0, 0};
        *(half8*)&Rb[tid * 8] = z;
    }

    // Transpose 8c x 4w -> 4 rows of half8, swizzled column group.
    const float* lf = (const float*)lv;   // lf[cc*4 + s]
    const float* rf = (const float*)rv;
    #pragma unroll
    for (int s = 0; s < 4; ++s) {
        const int w   = sw + s;
        const int col = (cg ^ (w & 7)) * 8;
        half8 lh, rh;
        #pragma unroll
        for (int cc = 0; cc < 8; ++cc) {
            lh[cc] = (_Float16)lf[cc * 4 + s];
            rh[cc] = (_Float16)rf[cc * 4 + s];
        }
        *(half8*)&Lb[w * 64 + col]        = lh;
        *(half8*)&Rb[(w + 64) * 64 + col] = rh;   // (w+64)&7 == w&7
    }
    __syncthreads();

    // ---------------- MFMA ----------------
    const int n     = lane & 15;        // B col / A row within tile
    const int q     = lane >> 4;        // quad
    const int wbase = wv * 32;          // this wave's 32-w range

    floatx4 acc[2][5];
    #pragma unroll
    for (int t = 0; t < 2; ++t)
        #pragma unroll
        for (int u = 0; u < 5; ++u)
            #pragma unroll
            for (int r = 0; r < 4; ++r)
                acc[t][u][r] = 0.0f;

    #pragma unroll
    for (int kk = 0; kk < 2; ++kk) {    // two K=32 chunks of the 64 channels
        const int col = ((kk * 4 + q) ^ (n & 7)) * 8;
        half8 bfrag[2], afrag[6];
        #pragma unroll
        for (int t = 0; t < 2; ++t)
            bfrag[t] = *(const half8*)&Lb[(wbase + t * 16 + n) * 64 + col];
        #pragma unroll
        for (int a = 0; a < 6; ++a)
            afrag[a] = *(const half8*)&Rb[(wbase + a * 16 + n) * 64 + col];
        #pragma unroll
        for (int t = 0; t < 2; ++t)
            #pragma unroll
            for (int u = 0; u < 5; ++u)
                acc[t][u] = __builtin_amdgcn_mfma_f32_16x16x32_f16(
                    afrag[t + u], bfrag[t], acc[t][u], 0, 0, 0);
    }

    // ---------------- epilogue ----------------
    // C/D layout: col = n (w), row m = q*4 + r (w' offset). d = 64-16u+n-m.
    const float scale = 1.0f / 64.0f;
    #pragma unroll
    for (int t = 0; t < 2; ++t) {
        const int w = wbase + t * 16 + n;
        #pragma unroll
        for (int u = 0; u < 5; ++u) {
            #pragma unroll
            for (int r = 0; r < 4; ++r) {
                const int d = 64 - 16 * u + n - (q * 4 + r);
                if (d >= 0 && d < DD) {
                    out[(((size_t)b * DD + d) * HH + h) * WW + w] =
                        acc[t][u][r] * scale;
                }
            }
        }
    }
}

extern "C" void kernel_launch(void* const* d_in, const int* in_sizes, int n_in,
                              void* d_out, int out_size, void* d_ws, size_t ws_size,
                              hipStream_t stream) {
    const float* left  = (const float*)d_in[0];
    const float* right = (const float*)d_in[1];
    float* out = (float*)d_out;

    dim3 grid(BB * HH);   // one block per (b, h)
    dim3 block(512);
    corr_volume_mfma<<<grid, block, 0, stream>>>(left, right, out);
}

// Round 5
// 186.667 us; speedup vs baseline: 1.3106x; 1.0139x over previous
//
#include <hip/hip_runtime.h>

typedef _Float16 half8 __attribute__((ext_vector_type(8)));
typedef float floatx4 __attribute__((ext_vector_type(4)));

#define BB 8
#define CC 64
#define HH 128
#define WW 256
#define DD 64
#define NROW 4            // (b,h) rows per block
#define GRID 256          // exactly 1 block per CU; NROW*GRID == BB*HH

// out[b,d,h,w] = (1/64) sum_c L[b,c,h,w] * R[b,c,h,w-d], 0 where w<d.
// Banded Gram via mfma_f32_16x16x32_f16 (see R3/R4 comments for the algebra).
// R5: software-pipelined over 4 rows per block — next row's 16 dwordx4 are
// issued into registers BEFORE the current row's MFMA+stores, so the
// __syncthreads() vmcnt(0) drain lands after a full compute+store phase of
// head start, and read/write streams overlap chip-wide instead of
// alternating phase-locked bursts (the R4 latency wall).
__global__ __launch_bounds__(512, 2)
void corr_volume_mfma(const float* __restrict__ left,
                      const float* __restrict__ right,
                      float* __restrict__ out) {
    __shared__ alignas(16) _Float16 Lb[256 * 64];   // [w][c^swz]      32 KiB
    __shared__ alignas(16) _Float16 Rb[320 * 64];   // [w'+64][c^swz]  40 KiB

    const int tid  = threadIdx.x;
    const int lane = tid & 63;
    const int wv   = tid >> 6;          // wave 0..7
    const int sw   = lane * 4;          // staged w rows sw..sw+3
    const int cg   = wv;                // staged channel group cg*8..cg*8+7

    const size_t chanStride = (size_t)HH * WW;      // 32768

    // Zero the w'<0 pad rows once (never overwritten; staging writes 64..319).
    {
        half8 z = {0, 0, 0, 0, 0, 0, 0, 0};
        *(half8*)&Rb[tid * 8] = z;
    }

    float4 lv[8], rv[8];

    // Prologue: issue row-0 loads immediately.
    {
        const int bh = blockIdx.x;
        const size_t rowBase = (size_t)(bh >> 7) * CC * chanStride
                             + (size_t)(bh & 127) * WW;
        const float* lp = left  + rowBase + (size_t)(cg * 8) * chanStride + sw;
        const float* rp = right + rowBase + (size_t)(cg * 8) * chanStride + sw;
        #pragma unroll
        for (int c = 0; c < 8; ++c) {
            lv[c] = *(const float4*)(lp + (size_t)c * chanStride);
            rv[c] = *(const float4*)(rp + (size_t)c * chanStride);
        }
    }

    const int n = lane & 15;            // MFMA col (w) / A row
    const int q = lane >> 4;            // quad
    const int wbase = wv * 32;          // this wave's w range
    const float scale = 1.0f / 64.0f;

    #pragma unroll
    for (int k = 0; k < NROW; ++k) {
        const int bh = blockIdx.x + k * GRID;
        const int b  = bh >> 7;
        const int h  = bh & 127;

        __syncthreads();   // prior row's LDS reads done (k=0: orders pad init)

        // Transpose 8c x 4w from regs -> LDS (waits only on this row's loads).
        {
            const float* lf = (const float*)lv;
            const float* rf = (const float*)rv;
            #pragma unroll
            for (int s = 0; s < 4; ++s) {
                const int w   = sw + s;
                const int col = (cg ^ (w & 7)) * 8;
                half8 lh, rh;
                #pragma unroll
                for (int c = 0; c < 8; ++c) {
                    lh[c] = (_Float16)lf[c * 4 + s];
                    rh[c] = (_Float16)rf[c * 4 + s];
                }
                *(half8*)&Lb[w * 64 + col]        = lh;
                *(half8*)&Rb[(w + 64) * 64 + col] = rh;
            }
        }
        __syncthreads();

        // Prefetch next row into registers — in flight through MFMA+stores.
        if (k + 1 < NROW) {
            const int bh2 = blockIdx.x + (k + 1) * GRID;
            const size_t rowBase2 = (size_t)(bh2 >> 7) * CC * chanStride
                                  + (size_t)(bh2 & 127) * WW;
            const float* lp = left  + rowBase2 + (size_t)(cg * 8) * chanStride + sw;
            const float* rp = right + rowBase2 + (size_t)(cg * 8) * chanStride + sw;
            #pragma unroll
            for (int c = 0; c < 8; ++c) {
                lv[c] = *(const float4*)(lp + (size_t)c * chanStride);
                rv[c] = *(const float4*)(rp + (size_t)c * chanStride);
            }
        }

        // ---------------- MFMA ----------------
        floatx4 acc[2][5];
        #pragma unroll
        for (int t = 0; t < 2; ++t)
            #pragma unroll
            for (int u = 0; u < 5; ++u)
                #pragma unroll
                for (int r = 0; r < 4; ++r)
                    acc[t][u][r] = 0.0f;

        #pragma unroll
        for (int kk = 0; kk < 2; ++kk) {
            const int col = ((kk * 4 + q) ^ (n & 7)) * 8;
            half8 bfrag[2], afrag[6];
            #pragma unroll
            for (int t = 0; t < 2; ++t)
                bfrag[t] = *(const half8*)&Lb[(wbase + t * 16 + n) * 64 + col];
            #pragma unroll
            for (int a = 0; a < 6; ++a)
                afrag[a] = *(const half8*)&Rb[(wbase + a * 16 + n) * 64 + col];
            #pragma unroll
            for (int t = 0; t < 2; ++t)
                #pragma unroll
                for (int u = 0; u < 5; ++u)
                    acc[t][u] = __builtin_amdgcn_mfma_f32_16x16x32_f16(
                        afrag[t + u], bfrag[t], acc[t][u], 0, 0, 0);
        }

        // ---------------- epilogue ----------------
        // C/D: col = n (w), row m = q*4+r (w' offset). d = 64-16u+n-m.
        #pragma unroll
        for (int t = 0; t < 2; ++t) {
            const int w = wbase + t * 16 + n;
            #pragma unroll
            for (int u = 0; u < 5; ++u) {
                #pragma unroll
                for (int r = 0; r < 4; ++r) {
                    const int d = 64 - 16 * u + n - (q * 4 + r);
                    if (d >= 0 && d < DD) {
                        out[(((size_t)b * DD + d) * HH + h) * WW + w] =
                            acc[t][u][r] * scale;
                    }
                }
            }
        }
    }
}

extern "C" void kernel_launch(void* const* d_in, const int* in_sizes, int n_in,
                              void* d_out, int out_size, void* d_ws, size_t ws_size,
                              hipStream_t stream) {
    const float* left  = (const float*)d_in[0];
    const float* right = (const float*)d_in[1];
    float* out = (float*)d_out;

    dim3 grid(GRID);    // 256 blocks = 1 per CU, each pipelines NROW rows
    dim3 block(512);
    corr_volume_mfma<<<grid, block, 0, stream>>>(left, right, out);
}